// Round 3
// baseline (1038.018 us; speedup 1.0000x reference)
//
#include <hip/hip_runtime.h>

#define NV 300
#define NA 12
#define ND 4
#define NM (NV*NA)
#define NS 1024
#define NG 1024

// workspace float offsets
#define W_VIEWS 0          // 900
#define W_GROT  900        // 32400
#define W_PKP   33300      // 43200
#define W_BATCH 76500
#define SB      134032     // per-batch stride (floats)

#define PB_GPT  0          // 3072
#define PB_ROT  3072       // 32400
#define PB_TB   35472      // 43200
#define PB_TBS  78672      // 43200
#define PB_TN1  121872     // 3600
#define PB_TN2  125472     // 3600
#define PB_VIND 129072     // 300 ints
#define PB_AIND 129372     // 3600 ints
#define PB_NN   132972     // 1024 ints

__constant__ float C_L[4][3]  = {{0.02f,0.f,0.f},{0.02f,0.01f,0.f},{0.02f,-0.01f,0.f},{0.f,0.f,0.f}};
__constant__ float C_LS[4][3] = {{0.02f,0.f,0.f},{0.02f,-0.01f,0.f},{0.02f,0.01f,0.f},{0.f,0.f,0.f}};

__device__ __forceinline__ void kp12(const float R[9], const float (*L)[3], float out[12]) {
#pragma unroll
    for (int k = 0; k < 4; ++k)
#pragma unroll
        for (int i = 0; i < 3; ++i)
            out[k*3+i] = R[i*3+0]*L[k][0] + R[i*3+1]*L[k][1] + R[i*3+2]*L[k][2];
}

__global__ void k_views(float* W) {
    int i = blockIdx.x*blockDim.x + threadIdx.x;
    if (i >= NV) return;
    const double PI = 3.14159265358979323846;
    double phi = (sqrt(5.0) - 1.0) * 0.5;
    double z = (2.0*i + 1.0)/(double)NV - 1.0;
    double r2 = 1.0 - z*z; r2 = r2 > 0.0 ? r2 : 0.0;
    double r = sqrt(r2);
    double ang = 2.0*PI*(double)i*phi;
    W[W_VIEWS + 3*i+0] = (float)(r*cos(ang));
    W[W_VIEWS + 3*i+1] = (float)(r*sin(ang));
    W[W_VIEWS + 3*i+2] = (float)z;
}

__global__ void k_grot(float* W) {
    int m = blockIdx.x*blockDim.x + threadIdx.x;
    if (m >= NM) return;
    int vi = m / NA, ai = m % NA;
    float tx = -W[W_VIEWS+3*vi+0], ty = -W[W_VIEWS+3*vi+1], tz = -W[W_VIEWS+3*vi+2];
    float nrm = sqrtf(tx*tx + ty*ty + tz*tz);
    float ax0 = tx/nrm, ax1 = ty/nrm, ax2 = tz/nrm;
    float ay0 = -ax1, ay1 = ax0, ay2 = 0.f;
    float n2 = sqrtf(ay0*ay0 + ay1*ay1 + ay2*ay2);
    if (n2 > 1e-8f) { float d = fmaxf(n2, 1e-12f); ay0 /= d; ay1 /= d; ay2 /= d; }
    else { ay0 = 0.f; ay1 = 1.f; ay2 = 0.f; }
    float az0 = ax1*ay2 - ax2*ay1;
    float az1 = ax2*ay0 - ax0*ay2;
    float az2 = ax0*ay1 - ax1*ay0;
    float angle = (float)(3.14159265358979323846/12.0*(double)ai);
    float c = cosf(angle), s = sinf(angle);
    // R2 (cols ax,ay,az) @ R1 (rot-x by angle)
    float G[9];
    G[0]=ax0; G[1]=ay0*c+az0*s; G[2]=-ay0*s+az0*c;
    G[3]=ax1; G[4]=ay1*c+az1*s; G[5]=-ay1*s+az1*c;
    G[6]=ax2; G[7]=ay2*c+az2*s; G[8]=-ay2*s+az2*c;
#pragma unroll
    for (int q=0;q<9;++q) W[W_GROT + 9*m + q] = G[q];
    float pk[12]; kp12(G, C_L, pk);
#pragma unroll
    for (int q=0;q<12;++q) W[W_PKP + 12*m + q] = pk[q];
}

__global__ void k_gpt(const float* __restrict__ pose, const float* __restrict__ gp, float* W) {
    int b = blockIdx.y;
    int g = blockIdx.x*blockDim.x + threadIdx.x;
    if (g >= NG) return;
    const float* P = pose + 12*b;
    float x = gp[((size_t)b*NG+g)*3+0], y = gp[((size_t)b*NG+g)*3+1], z = gp[((size_t)b*NG+g)*3+2];
    float* o = W + W_BATCH + (size_t)b*SB + PB_GPT + 3*g;
    o[0] = P[0]*x + P[1]*y + P[2]*z  + P[3];
    o[1] = P[4]*x + P[5]*y + P[6]*z  + P[7];
    o[2] = P[8]*x + P[9]*y + P[10]*z + P[11];
}

__global__ void k_vind(const float* __restrict__ pose, float* W) {
    int b = blockIdx.x;
    const float* P = pose + 12*b;
    __shared__ float vt[NV][3];
    __shared__ float vn[NV];
    int tid = threadIdx.x;
    if (tid < NV) {
        float x = W[W_VIEWS+3*tid], y = W[W_VIEWS+3*tid+1], z = W[W_VIEWS+3*tid+2];
        float a = P[0]*x+P[1]*y+P[2]*z;
        float c = P[4]*x+P[5]*y+P[6]*z;
        float d = P[8]*x+P[9]*y+P[10]*z;
        vt[tid][0]=a; vt[tid][1]=c; vt[tid][2]=d;
        vn[tid] = a*a + c*c + d*d;
    }
    __syncthreads();
    if (tid < NV) {
        float x = W[W_VIEWS+3*tid], y = W[W_VIEWS+3*tid+1], z = W[W_VIEWS+3*tid+2];
        float na = x*x + y*y + z*z;
        float best = INFINITY; int bi = 0;
        for (int v2 = 0; v2 < NV; ++v2) {
            float d = na + vn[v2] - 2.f*(x*vt[v2][0] + y*vt[v2][1] + z*vt[v2][2]);
            if (d < best) { best = d; bi = v2; }
        }
        ((int*)W)[W_BATCH + (size_t)b*SB + PB_VIND + tid] = bi;
    }
}

__global__ void k_align(const float* __restrict__ pose, float* W) {
    int v = blockIdx.x, b = blockIdx.y;
    float* WB = W + W_BATCH + (size_t)b*SB;
    int* IB = (int*)W + W_BATCH + (size_t)b*SB;
    int vi = IB[PB_VIND + v];
    const float* P = pose + 12*b;
    __shared__ float rtr[NA][9];
    __shared__ float tk[NA][12], tks[NA][12];
    int a = threadIdx.x;
    if (a < NA) {
        const float* G = W + W_GROT + 9*(vi*NA + a);
        float rt[9];
#pragma unroll
        for (int i=0;i<3;++i)
#pragma unroll
            for (int j=0;j<3;++j)
                rt[i*3+j] = P[i*4+0]*G[0*3+j] + P[i*4+1]*G[1*3+j] + P[i*4+2]*G[2*3+j];
#pragma unroll
        for (int q=0;q<9;++q) rtr[a][q]=rt[q];
        float t1[12], t2[12];
        kp12(rt, C_L, t1); kp12(rt, C_LS, t2);
#pragma unroll
        for (int k=0;k<12;++k) { tk[a][k]=t1[k]; tks[a][k]=t2[k]; }
    }
    __syncthreads();
    if (a < NA) {
        const float* pk = W + W_PKP + 12*(v*NA + a);
        float pkl[12];
#pragma unroll
        for (int k=0;k<12;++k) pkl[k]=pk[k];
        float m1=INFINITY, m2=INFINITY; int i1=0, i2=0;
        for (int ap=0; ap<NA; ++ap) {
            float d1=0.f, d2=0.f;
#pragma unroll
            for (int k=0;k<12;++k) {
                float e1 = pkl[k]-tk[ap][k];  d1 += e1*e1;
                float e2 = pkl[k]-tks[ap][k]; d2 += e2*e2;
            }
            if (d1 < m1) { m1=d1; i1=ap; }
            if (d2 < m2) { m2=d2; i2=ap; }
        }
        int ind = (m1 < m2) ? i1 : i2;
        int mi = v*NA + a;
        IB[PB_AIND + mi] = ind;
        float sel[9];
#pragma unroll
        for (int q=0;q<9;++q) { sel[q]=rtr[ind][q]; WB[PB_ROT + 9*mi + q] = sel[q]; }
        float tb[12], tbs[12];
        kp12(sel, C_L, tb); kp12(sel, C_LS, tbs);
        float s1=0.f, s2=0.f;
#pragma unroll
        for (int k=0;k<12;++k) {
            WB[PB_TB +12*mi+k]=tb[k];  s1 += tb[k]*tb[k];
            WB[PB_TBS+12*mi+k]=tbs[k]; s2 += tbs[k]*tbs[k];
        }
        WB[PB_TN1+mi]=s1; WB[PB_TN2+mi]=s2;
    }
}

__global__ void k_nn(const float* __restrict__ pc, float* W) {
    int b = blockIdx.y;
    int s = blockIdx.x*blockDim.x + threadIdx.x;
    float* WB = W + W_BATCH + (size_t)b*SB;
    __shared__ float gx[NG], gy[NG], gz[NG], gn[NG];
    for (int i = threadIdx.x; i < NG; i += blockDim.x) {
        float x = WB[PB_GPT+3*i], y = WB[PB_GPT+3*i+1], z = WB[PB_GPT+3*i+2];
        gx[i]=x; gy[i]=y; gz[i]=z; gn[i]=x*x+y*y+z*z;
    }
    __syncthreads();
    float px = pc[((size_t)b*NS+s)*3+0], py = pc[((size_t)b*NS+s)*3+1], pz = pc[((size_t)b*NS+s)*3+2];
    float pn = px*px+py*py+pz*pz;
    float best = INFINITY; int bi = 0;
    for (int g = 0; g < NG; ++g) {
        float d = pn + gn[g] - 2.f*(px*gx[g]+py*gy[g]+pz*gz[g]);
        if (d < best) { best = d; bi = g; }
    }
    ((int*)W)[W_BATCH + (size_t)b*SB + PB_NN + s] = bi;
}

__global__ void k_final(const float* __restrict__ r6p, const float* __restrict__ dpp,
                        const float* __restrict__ labels, const float* __restrict__ offsets,
                        float* __restrict__ W, float* __restrict__ out, int B) {
    int b = blockIdx.y;
    int s = blockIdx.x*blockDim.x + threadIdx.x;
    float* WB = W + W_BATCH + (size_t)b*SB;
    const int* IB = (const int*)W + W_BATCH + (size_t)b*SB;

    const float* r6 = r6p + 6*((size_t)b*NS+s);
    float a1x=r6[0],a1y=r6[1],a1z=r6[2],a2x=r6[3],a2y=r6[4],a2z=r6[5];
    float n1 = sqrtf(a1x*a1x+a1y*a1y+a1z*a1z);
    float b1x=a1x/n1, b1y=a1y/n1, b1z=a1z/n1;
    float dt = b1x*a2x+b1y*a2y+b1z*a2z;
    float p2x=a2x-dt*b1x, p2y=a2y-dt*b1y, p2z=a2z-dt*b1z;
    float n2 = sqrtf(p2x*p2x+p2y*p2y+p2z*p2z);
    float b2x=p2x/n2, b2y=p2y/n2, b2z=p2z/n2;
    float b3x=b1y*b2z-b1z*b2y, b3y=b1z*b2x-b1x*b2z, b3z=b1x*b2y-b1y*b2x;
    float Rp[9] = {b1x,b1y,b1z, b2x,b2y,b2z, b3x,b3y,b3z};
    float pb[12]; kp12(Rp, C_L, pb);
    float Pn = 0.f;
#pragma unroll
    for (int k=0;k<12;++k) Pn += pb[k]*pb[k];

    float m1=INFINITY, m2=INFINITY; int i1=0, i2=0;
    for (int j = 0; j < NM; ++j) {
        const float* tb  = WB + PB_TB  + 12*j;
        const float* tbs = WB + PB_TBS + 12*j;
        float dot1 = 0.f, dot2 = 0.f;
#pragma unroll
        for (int k=0;k<12;++k) { dot1 += pb[k]*tb[k]; dot2 += pb[k]*tbs[k]; }
        float d1 = Pn + WB[PB_TN1+j] - 2.f*dot1;
        float d2 = Pn + WB[PB_TN2+j] - 2.f*dot2;
        if (d1 < m1) { m1=d1; i1=j; }
        if (d2 < m2) { m2=d2; i2=j; }
    }
    int rot_ind = (m1 < m2) ? i1 : i2;

    float dp = dpp[(size_t)b*NS+s];
    float bd = INFINITY; int di = 0;
#pragma unroll
    for (int d = 0; d < ND; ++d) {
        float dv = (float)(0.01 + 0.01*(double)d);
        float ad = fabsf(dp - dv);
        if (ad < bd) { bd = ad; di = d; }
    }

    int nn_s = IB[PB_NN+s];
    int v_out = rot_ind / NA;
    int vi = IB[PB_VIND + v_out];
    int ai = IB[PB_AIND + rot_ind];
    size_t lidx = ((((size_t)b*NG+nn_s)*NV + vi)*NA + ai)*ND + di;
    float gs = labels[lidx];
    float gw = offsets[lidx];

    int bs = b*NS + s;
    int oRot = B*NS*3;
    int oSc  = oRot + B*NS*6;
    int oWd  = oSc  + B*NS;
    int oDp  = oWd  + B*NS;
    int oWid = oDp  + B*NS;
    int oSid = oWid + B*NS;

    const float* gsel = WB + PB_GPT + 3*nn_s;
    out[3*bs+0]=gsel[0]; out[3*bs+1]=gsel[1]; out[3*bs+2]=gsel[2];
    const float* Rsel = WB + PB_ROT + 9*rot_ind;
#pragma unroll
    for (int q=0;q<6;++q) out[oRot + 6*bs + q] = Rsel[q];

    bool mask = (gs > 0.f) && (gw <= 0.1f);
    float sc = mask ? (1.1f - gs) : 0.f;
    out[oSc + bs] = sc;
    out[oWd + bs] = gw;
    out[oDp + bs] = (float)(0.01 + 0.01*(double)di);

    int wid = 0;
    wid += (0.02f < gw); wid += (0.04f < gw); wid += (0.06f < gw); wid += (0.08f < gw);
    const float sbins[9] = {0.1f,0.2f,0.3f,0.4f,0.5f,0.6f,0.7f,0.8f,0.9f};
    int sid = 0;
#pragma unroll
    for (int i=0;i<9;++i) sid += (sbins[i] < sc) ? 1 : 0;
    out[oWid + bs] = (float)wid;
    out[oSid + bs] = (float)sid;
}

extern "C" void kernel_launch(void* const* d_in, const int* in_sizes, int n_in,
                              void* d_out, int out_size, void* d_ws, size_t ws_size,
                              hipStream_t stream) {
    const float* pc      = (const float*)d_in[0];
    const float* pose    = (const float*)d_in[1];
    const float* gp      = (const float*)d_in[2];
    const float* labels  = (const float*)d_in[3];
    const float* offsets = (const float*)d_in[4];
    const float* r6      = (const float*)d_in[5];
    const float* dpp     = (const float*)d_in[6];
    float* W   = (float*)d_ws;
    float* out = (float*)d_out;
    int B = in_sizes[1] / 12;

    hipLaunchKernelGGL(k_views, dim3(2), dim3(256), 0, stream, W);
    hipLaunchKernelGGL(k_grot,  dim3((NM+255)/256), dim3(256), 0, stream, W);
    hipLaunchKernelGGL(k_gpt,   dim3(NG/256, B), dim3(256), 0, stream, pose, gp, W);
    hipLaunchKernelGGL(k_vind,  dim3(B), dim3(320), 0, stream, pose, W);
    hipLaunchKernelGGL(k_align, dim3(NV, B), dim3(64), 0, stream, pose, W);
    hipLaunchKernelGGL(k_nn,    dim3(NS/256, B), dim3(256), 0, stream, pc, W);
    hipLaunchKernelGGL(k_final, dim3(NS/256, B), dim3(256), 0, stream, r6, dpp, labels, offsets, W, out, B);
}

// Round 5
// 337.050 us; speedup vs baseline: 3.0797x; 3.0797x over previous
//
#include <hip/hip_runtime.h>

#define NV 300
#define NA 12
#define ND 4
#define NM (NV*NA)
#define NS 1024
#define NG 1024

// workspace float offsets
#define W_VIEWS 0          // 900
#define W_GROT  900        // 32400
#define W_PKP   33300      // 43200
#define W_BATCH 76500
#define SB      134032     // per-batch stride (floats)

#define PB_GPT  0          // 3072
#define PB_ROT  3072       // 32400
#define PB_TB   35472      // 43200 (transposed: [12][NM])
#define PB_TBS  78672      // 43200 (transposed: [12][NM])
#define PB_TN1  121872     // 3600
#define PB_TN2  125472     // 3600
#define PB_VIND 129072     // 300 ints
#define PB_AIND 129372     // 3600 ints
#define PB_NN   132972     // 1024 ints

__constant__ float C_L[4][3]  = {{0.02f,0.f,0.f},{0.02f,0.01f,0.f},{0.02f,-0.01f,0.f},{0.f,0.f,0.f}};
__constant__ float C_LS[4][3] = {{0.02f,0.f,0.f},{0.02f,-0.01f,0.f},{0.02f,0.01f,0.f},{0.f,0.f,0.f}};

__device__ __forceinline__ void kp12(const float R[9], const float (*L)[3], float out[12]) {
#pragma unroll
    for (int k = 0; k < 4; ++k)
#pragma unroll
        for (int i = 0; i < 3; ++i)
            out[k*3+i] = R[i*3+0]*L[k][0] + R[i*3+1]*L[k][1] + R[i*3+2]*L[k][2];
}

// fp64 Fibonacci-sphere view i (identical formula to numpy reference)
__device__ __forceinline__ void view_d(int i, float* vx, float* vy, float* vz) {
    const double PI = 3.14159265358979323846;
    double phi = (sqrt(5.0) - 1.0) * 0.5;
    double z = (2.0*i + 1.0)/(double)NV - 1.0;
    double r2 = 1.0 - z*z; r2 = r2 > 0.0 ? r2 : 0.0;
    double r = sqrt(r2);
    double ang = 2.0*PI*(double)i*phi;
    *vx = (float)(r*cos(ang));
    *vy = (float)(r*sin(ang));
    *vz = (float)z;
}

// views + GRASP_ROT + template keypoints, one kernel
__global__ void k_setup(float* W) {
    int m = blockIdx.x*blockDim.x + threadIdx.x;
    if (m >= NM) return;
    if (m < NV) {
        float x,y,z; view_d(m, &x,&y,&z);
        W[W_VIEWS + 3*m+0] = x; W[W_VIEWS + 3*m+1] = y; W[W_VIEWS + 3*m+2] = z;
    }
    int vi = m / NA, ai = m % NA;
    float vx,vy,vz; view_d(vi, &vx,&vy,&vz);
    float tx = -vx, ty = -vy, tz = -vz;
    float nrm = sqrtf(tx*tx + ty*ty + tz*tz);
    float ax0 = tx/nrm, ax1 = ty/nrm, ax2 = tz/nrm;
    float ay0 = -ax1, ay1 = ax0, ay2 = 0.f;
    float n2 = sqrtf(ay0*ay0 + ay1*ay1 + ay2*ay2);
    if (n2 > 1e-8f) { float d = fmaxf(n2, 1e-12f); ay0 /= d; ay1 /= d; ay2 /= d; }
    else { ay0 = 0.f; ay1 = 1.f; ay2 = 0.f; }
    float az0 = ax1*ay2 - ax2*ay1;
    float az1 = ax2*ay0 - ax0*ay2;
    float az2 = ax0*ay1 - ax1*ay0;
    float angle = (float)(3.14159265358979323846/12.0*(double)ai);
    float c = cosf(angle), s = sinf(angle);
    float G[9];
    G[0]=ax0; G[1]=ay0*c+az0*s; G[2]=-ay0*s+az0*c;
    G[3]=ax1; G[4]=ay1*c+az1*s; G[5]=-ay1*s+az1*c;
    G[6]=ax2; G[7]=ay2*c+az2*s; G[8]=-ay2*s+az2*c;
#pragma unroll
    for (int q=0;q<9;++q) W[W_GROT + 9*m + q] = G[q];
    float pk[12]; kp12(G, C_L, pk);
#pragma unroll
    for (int q=0;q<12;++q) W[W_PKP + 12*m + q] = pk[q];
}

__global__ void k_gpt(const float* __restrict__ pose, const float* __restrict__ gp, float* W) {
    int b = blockIdx.y;
    int g = blockIdx.x*blockDim.x + threadIdx.x;
    if (g >= NG) return;
    const float* P = pose + 12*b;
    float x = gp[((size_t)b*NG+g)*3+0], y = gp[((size_t)b*NG+g)*3+1], z = gp[((size_t)b*NG+g)*3+2];
    float* o = W + W_BATCH + (size_t)b*SB + PB_GPT + 3*g;
    o[0] = P[0]*x + P[1]*y + P[2]*z  + P[3];
    o[1] = P[4]*x + P[5]*y + P[6]*z  + P[7];
    o[2] = P[8]*x + P[9]*y + P[10]*z + P[11];
}

__global__ void k_vind(const float* __restrict__ pose, float* W) {
    int b = blockIdx.x;
    const float* P = pose + 12*b;
    __shared__ float vt[NV][3];
    __shared__ float vn[NV];
    int tid = threadIdx.x;
    if (tid < NV) {
        float x = W[W_VIEWS+3*tid], y = W[W_VIEWS+3*tid+1], z = W[W_VIEWS+3*tid+2];
        float a = P[0]*x+P[1]*y+P[2]*z;
        float c = P[4]*x+P[5]*y+P[6]*z;
        float d = P[8]*x+P[9]*y+P[10]*z;
        vt[tid][0]=a; vt[tid][1]=c; vt[tid][2]=d;
        vn[tid] = a*a + c*c + d*d;
    }
    __syncthreads();
    if (tid < NV) {
        float x = W[W_VIEWS+3*tid], y = W[W_VIEWS+3*tid+1], z = W[W_VIEWS+3*tid+2];
        float na = x*x + y*y + z*z;
        float best = INFINITY; int bi = 0;
        for (int v2 = 0; v2 < NV; ++v2) {
            float d = na + vn[v2] - 2.f*(x*vt[v2][0] + y*vt[v2][1] + z*vt[v2][2]);
            if (d < best) { best = d; bi = v2; }
        }
        ((int*)W)[W_BATCH + (size_t)b*SB + PB_VIND + tid] = bi;
    }
}

__global__ void k_align(const float* __restrict__ pose, float* W) {
    int v = blockIdx.x, b = blockIdx.y;
    float* WB = W + W_BATCH + (size_t)b*SB;
    int* IB = (int*)W + W_BATCH + (size_t)b*SB;
    int vi = IB[PB_VIND + v];
    const float* P = pose + 12*b;
    __shared__ float rtr[NA][9];
    __shared__ float tk[NA][12], tks[NA][12];
    int a = threadIdx.x;
    if (a < NA) {
        const float* G = W + W_GROT + 9*(vi*NA + a);
        float rt[9];
#pragma unroll
        for (int i=0;i<3;++i)
#pragma unroll
            for (int j=0;j<3;++j)
                rt[i*3+j] = P[i*4+0]*G[0*3+j] + P[i*4+1]*G[1*3+j] + P[i*4+2]*G[2*3+j];
#pragma unroll
        for (int q=0;q<9;++q) rtr[a][q]=rt[q];
        float t1[12], t2[12];
        kp12(rt, C_L, t1); kp12(rt, C_LS, t2);
#pragma unroll
        for (int k=0;k<12;++k) { tk[a][k]=t1[k]; tks[a][k]=t2[k]; }
    }
    __syncthreads();
    if (a < NA) {
        const float* pk = W + W_PKP + 12*(v*NA + a);
        float pkl[12];
#pragma unroll
        for (int k=0;k<12;++k) pkl[k]=pk[k];
        float m1=INFINITY, m2=INFINITY; int i1=0, i2=0;
        for (int ap=0; ap<NA; ++ap) {
            float d1=0.f, d2=0.f;
#pragma unroll
            for (int k=0;k<12;++k) {
                float e1 = pkl[k]-tk[ap][k];  d1 += e1*e1;
                float e2 = pkl[k]-tks[ap][k]; d2 += e2*e2;
            }
            if (d1 < m1) { m1=d1; i1=ap; }
            if (d2 < m2) { m2=d2; i2=ap; }
        }
        int ind = (m1 < m2) ? i1 : i2;
        int mi = v*NA + a;
        IB[PB_AIND + mi] = ind;
        float sel[9];
#pragma unroll
        for (int q=0;q<9;++q) { sel[q]=rtr[ind][q]; WB[PB_ROT + 9*mi + q] = sel[q]; }
        float tb[12], tbs[12];
        kp12(sel, C_L, tb); kp12(sel, C_LS, tbs);
        float s1=0.f, s2=0.f;
#pragma unroll
        for (int k=0;k<12;++k) {
            WB[PB_TB +k*NM+mi]=tb[k];  s1 += tb[k]*tb[k];   // transposed [12][NM]
            WB[PB_TBS+k*NM+mi]=tbs[k]; s2 += tbs[k]*tbs[k]; // transposed [12][NM]
        }
        WB[PB_TN1+mi]=s1; WB[PB_TN2+mi]=s2;
    }
}

// wave-per-seed NN: 4 waves/block, LDS-staged grasp points
__global__ void k_nn(const float* __restrict__ pc, float* W) {
    int b = blockIdx.y;
    float* WB = W + W_BATCH + (size_t)b*SB;
    __shared__ float gx[NG], gy[NG], gz[NG], gn[NG];
    for (int i = threadIdx.x; i < NG; i += 256) {
        float x = WB[PB_GPT+3*i], y = WB[PB_GPT+3*i+1], z = WB[PB_GPT+3*i+2];
        gx[i]=x; gy[i]=y; gz[i]=z; gn[i]=x*x+y*y+z*z;
    }
    __syncthreads();
    int wv = threadIdx.x >> 6, lane = threadIdx.x & 63;
    int s = blockIdx.x*4 + wv;
    float px = pc[((size_t)b*NS+s)*3+0], py = pc[((size_t)b*NS+s)*3+1], pz = pc[((size_t)b*NS+s)*3+2];
    float pn = px*px+py*py+pz*pz;
    float best = INFINITY; int bi = 0x7fffffff;
    for (int g = lane; g < NG; g += 64) {
        float d = pn + gn[g] - 2.f*(px*gx[g]+py*gy[g]+pz*gz[g]);
        if (d < best) { best = d; bi = g; }
    }
#pragma unroll
    for (int off = 32; off > 0; off >>= 1) {
        float ov = __shfl_down(best, off); int oi = __shfl_down(bi, off);
        if (ov < best || (ov == best && oi < bi)) { best = ov; bi = oi; }
    }
    if (lane == 0) ((int*)W)[W_BATCH + (size_t)b*SB + PB_NN + s] = bi;
}

// wave-per-seed rotation match: 4 waves/block, coalesced transposed TB/TBS
__global__ void k_final(const float* __restrict__ r6p, const float* __restrict__ dpp,
                        const float* __restrict__ labels, const float* __restrict__ offsets,
                        float* __restrict__ W, float* __restrict__ out, int B) {
    int b = blockIdx.y;
    int wv = threadIdx.x >> 6, lane = threadIdx.x & 63;
    int s = blockIdx.x*4 + wv;
    float* WB = W + W_BATCH + (size_t)b*SB;
    const int* IB = (const int*)W + W_BATCH + (size_t)b*SB;

    const float* r6 = r6p + 6*((size_t)b*NS+s);
    float a1x=r6[0],a1y=r6[1],a1z=r6[2],a2x=r6[3],a2y=r6[4],a2z=r6[5];
    float n1 = sqrtf(a1x*a1x+a1y*a1y+a1z*a1z);
    float b1x=a1x/n1, b1y=a1y/n1, b1z=a1z/n1;
    float dt = b1x*a2x+b1y*a2y+b1z*a2z;
    float p2x=a2x-dt*b1x, p2y=a2y-dt*b1y, p2z=a2z-dt*b1z;
    float n2 = sqrtf(p2x*p2x+p2y*p2y+p2z*p2z);
    float b2x=p2x/n2, b2y=p2y/n2, b2z=p2z/n2;
    float b3x=b1y*b2z-b1z*b2y, b3y=b1z*b2x-b1x*b2z, b3z=b1x*b2y-b1y*b2x;
    float Rp[9] = {b1x,b1y,b1z, b2x,b2y,b2z, b3x,b3y,b3z};
    float pb[12]; kp12(Rp, C_L, pb);
    float Pn = 0.f;
#pragma unroll
    for (int k=0;k<12;++k) Pn += pb[k]*pb[k];

    float m1=INFINITY, m2=INFINITY; int i1=0x7fffffff, i2=0x7fffffff;
    for (int j = lane; j < NM; j += 64) {
        float dot1 = 0.f, dot2 = 0.f;
#pragma unroll
        for (int k=0;k<12;++k) {
            dot1 += pb[k]*WB[PB_TB +k*NM+j];
            dot2 += pb[k]*WB[PB_TBS+k*NM+j];
        }
        float d1 = Pn + WB[PB_TN1+j] - 2.f*dot1;
        float d2 = Pn + WB[PB_TN2+j] - 2.f*dot2;
        if (d1 < m1) { m1=d1; i1=j; }
        if (d2 < m2) { m2=d2; i2=j; }
    }
#pragma unroll
    for (int off = 32; off > 0; off >>= 1) {
        float o1 = __shfl_down(m1, off); int oi1 = __shfl_down(i1, off);
        if (o1 < m1 || (o1 == m1 && oi1 < i1)) { m1 = o1; i1 = oi1; }
        float o2 = __shfl_down(m2, off); int oi2 = __shfl_down(i2, off);
        if (o2 < m2 || (o2 == m2 && oi2 < i2)) { m2 = o2; i2 = oi2; }
    }
    if (lane != 0) return;
    int rot_ind = (m1 < m2) ? i1 : i2;

    float dp = dpp[(size_t)b*NS+s];
    float bd = INFINITY; int di = 0;
#pragma unroll
    for (int d = 0; d < ND; ++d) {
        float dv = (float)(0.01 + 0.01*(double)d);
        float ad = fabsf(dp - dv);
        if (ad < bd) { bd = ad; di = d; }
    }

    int nn_s = IB[PB_NN+s];
    int v_out = rot_ind / NA;
    int vi = IB[PB_VIND + v_out];
    int ai = IB[PB_AIND + rot_ind];
    size_t lidx = ((((size_t)b*NG+nn_s)*NV + vi)*NA + ai)*ND + di;
    float gs = labels[lidx];
    float gw = offsets[lidx];

    int bs = b*NS + s;
    int oRot = B*NS*3;
    int oSc  = oRot + B*NS*6;
    int oWd  = oSc  + B*NS;
    int oDp  = oWd  + B*NS;
    int oWid = oDp  + B*NS;
    int oSid = oWid + B*NS;

    const float* gsel = WB + PB_GPT + 3*nn_s;
    out[3*bs+0]=gsel[0]; out[3*bs+1]=gsel[1]; out[3*bs+2]=gsel[2];
    const float* Rsel = WB + PB_ROT + 9*rot_ind;
#pragma unroll
    for (int q=0;q<6;++q) out[oRot + 6*bs + q] = Rsel[q];

    bool mask = (gs > 0.f) && (gw <= 0.1f);
    float sc = mask ? (1.1f - gs) : 0.f;
    out[oSc + bs] = sc;
    out[oWd + bs] = gw;
    out[oDp + bs] = (float)(0.01 + 0.01*(double)di);

    int wid = 0;
    wid += (0.02f < gw); wid += (0.04f < gw); wid += (0.06f < gw); wid += (0.08f < gw);
    const float sbins[9] = {0.1f,0.2f,0.3f,0.4f,0.5f,0.6f,0.7f,0.8f,0.9f};
    int sid = 0;
#pragma unroll
    for (int i=0;i<9;++i) sid += (sbins[i] < sc) ? 1 : 0;
    out[oWid + bs] = (float)wid;
    out[oSid + bs] = (float)sid;
}

extern "C" void kernel_launch(void* const* d_in, const int* in_sizes, int n_in,
                              void* d_out, int out_size, void* d_ws, size_t ws_size,
                              hipStream_t stream) {
    const float* pc      = (const float*)d_in[0];
    const float* pose    = (const float*)d_in[1];
    const float* gp      = (const float*)d_in[2];
    const float* labels  = (const float*)d_in[3];
    const float* offsets = (const float*)d_in[4];
    const float* r6      = (const float*)d_in[5];
    const float* dpp     = (const float*)d_in[6];
    float* W   = (float*)d_ws;
    float* out = (float*)d_out;
    int B = in_sizes[1] / 12;

    hipLaunchKernelGGL(k_setup, dim3((NM+255)/256), dim3(256), 0, stream, W);
    hipLaunchKernelGGL(k_gpt,   dim3(NG/256, B), dim3(256), 0, stream, pose, gp, W);
    hipLaunchKernelGGL(k_vind,  dim3(B), dim3(320), 0, stream, pose, W);
    hipLaunchKernelGGL(k_align, dim3(NV, B), dim3(64), 0, stream, pose, W);
    hipLaunchKernelGGL(k_nn,    dim3(NS/4, B), dim3(256), 0, stream, pc, W);
    hipLaunchKernelGGL(k_final, dim3(NS/4, B), dim3(256), 0, stream, r6, dpp, labels, offsets, W, out, B);
}

// Round 6
// 266.345 us; speedup vs baseline: 3.8973x; 1.2655x over previous
//
#include <hip/hip_runtime.h>

#define NV 300
#define NA 12
#define ND 4
#define NM (NV*NA)
#define NS 1024
#define NG 1024

// workspace float offsets
#define W_VIEWS 0          // 900
#define W_GROT  900        // 32400
#define W_PKP   33300      // 43200
#define W_BATCH 76500
#define SB      134032     // per-batch stride (floats)

#define PB_GPT  0          // 3072
#define PB_ROT  3072       // 32400
#define PB_TB   35472      // 43200 (transposed: [12][NM])
#define PB_TBS  78672      // 43200 (transposed: [12][NM])
#define PB_TN1  121872     // 3600
#define PB_TN2  125472     // 3600
#define PB_VIND 129072     // 300 ints
#define PB_AIND 129372     // 3600 ints
#define PB_NN   132972     // 1024 ints

__constant__ float C_L[4][3]  = {{0.02f,0.f,0.f},{0.02f,0.01f,0.f},{0.02f,-0.01f,0.f},{0.f,0.f,0.f}};
__constant__ float C_LS[4][3] = {{0.02f,0.f,0.f},{0.02f,-0.01f,0.f},{0.02f,0.01f,0.f},{0.f,0.f,0.f}};

__device__ __forceinline__ void kp12(const float R[9], const float (*L)[3], float out[12]) {
#pragma unroll
    for (int k = 0; k < 4; ++k)
#pragma unroll
        for (int i = 0; i < 3; ++i)
            out[k*3+i] = R[i*3+0]*L[k][0] + R[i*3+1]*L[k][1] + R[i*3+2]*L[k][2];
}

// fp64 Fibonacci-sphere views (identical formula to numpy reference), 300 threads
__global__ void k_views(float* W) {
    int i = blockIdx.x*blockDim.x + threadIdx.x;
    if (i >= NV) return;
    const double PI = 3.14159265358979323846;
    double phi = (sqrt(5.0) - 1.0) * 0.5;
    double z = (2.0*i + 1.0)/(double)NV - 1.0;
    double r2 = 1.0 - z*z; r2 = r2 > 0.0 ? r2 : 0.0;
    double r = sqrt(r2);
    double ang = 2.0*PI*(double)i*phi;
    W[W_VIEWS + 3*i+0] = (float)(r*cos(ang));
    W[W_VIEWS + 3*i+1] = (float)(r*sin(ang));
    W[W_VIEWS + 3*i+2] = (float)z;
}

__global__ void k_grot(float* W) {
    int m = blockIdx.x*blockDim.x + threadIdx.x;
    if (m >= NM) return;
    int vi = m / NA, ai = m % NA;
    float tx = -W[W_VIEWS+3*vi+0], ty = -W[W_VIEWS+3*vi+1], tz = -W[W_VIEWS+3*vi+2];
    float nrm = sqrtf(tx*tx + ty*ty + tz*tz);
    float ax0 = tx/nrm, ax1 = ty/nrm, ax2 = tz/nrm;
    float ay0 = -ax1, ay1 = ax0, ay2 = 0.f;
    float n2 = sqrtf(ay0*ay0 + ay1*ay1 + ay2*ay2);
    if (n2 > 1e-8f) { float d = fmaxf(n2, 1e-12f); ay0 /= d; ay1 /= d; ay2 /= d; }
    else { ay0 = 0.f; ay1 = 1.f; ay2 = 0.f; }
    float az0 = ax1*ay2 - ax2*ay1;
    float az1 = ax2*ay0 - ax0*ay2;
    float az2 = ax0*ay1 - ax1*ay0;
    float angle = (float)(3.14159265358979323846/12.0*(double)ai);
    float c = cosf(angle), s = sinf(angle);
    float G[9];
    G[0]=ax0; G[1]=ay0*c+az0*s; G[2]=-ay0*s+az0*c;
    G[3]=ax1; G[4]=ay1*c+az1*s; G[5]=-ay1*s+az1*c;
    G[6]=ax2; G[7]=ay2*c+az2*s; G[8]=-ay2*s+az2*c;
#pragma unroll
    for (int q=0;q<9;++q) W[W_GROT + 9*m + q] = G[q];
    float pk[12]; kp12(G, C_L, pk);
#pragma unroll
    for (int q=0;q<12;++q) W[W_PKP + 12*m + q] = pk[q];
}

__global__ void k_gpt(const float* __restrict__ pose, const float* __restrict__ gp, float* W) {
    int b = blockIdx.y;
    int g = blockIdx.x*blockDim.x + threadIdx.x;
    if (g >= NG) return;
    const float* P = pose + 12*b;
    float x = gp[((size_t)b*NG+g)*3+0], y = gp[((size_t)b*NG+g)*3+1], z = gp[((size_t)b*NG+g)*3+2];
    float* o = W + W_BATCH + (size_t)b*SB + PB_GPT + 3*g;
    o[0] = P[0]*x + P[1]*y + P[2]*z  + P[3];
    o[1] = P[4]*x + P[5]*y + P[6]*z  + P[7];
    o[2] = P[8]*x + P[9]*y + P[10]*z + P[11];
}

// wave-per-view argmin: grid (NV/4, B), block 256
__global__ void k_vind(const float* __restrict__ pose, float* W) {
    int b = blockIdx.y;
    const float* P = pose + 12*b;
    __shared__ float vtx[NV], vty[NV], vtz[NV], vn[NV];
    for (int i = threadIdx.x; i < NV; i += 256) {
        float x = W[W_VIEWS+3*i], y = W[W_VIEWS+3*i+1], z = W[W_VIEWS+3*i+2];
        float a = P[0]*x+P[1]*y+P[2]*z;
        float c = P[4]*x+P[5]*y+P[6]*z;
        float d = P[8]*x+P[9]*y+P[10]*z;
        vtx[i]=a; vty[i]=c; vtz[i]=d;
        vn[i] = a*a + c*c + d*d;
    }
    __syncthreads();
    int wv = threadIdx.x >> 6, lane = threadIdx.x & 63;
    int v = blockIdx.x*4 + wv;  // 75*4 = 300 exact
    float x = W[W_VIEWS+3*v], y = W[W_VIEWS+3*v+1], z = W[W_VIEWS+3*v+2];
    float na = x*x + y*y + z*z;
    float best = INFINITY; int bi = 0x7fffffff;
    for (int v2 = lane; v2 < NV; v2 += 64) {
        float d = na + vn[v2] - 2.f*(x*vtx[v2] + y*vty[v2] + z*vtz[v2]);
        if (d < best) { best = d; bi = v2; }
    }
#pragma unroll
    for (int off = 32; off > 0; off >>= 1) {
        float ov = __shfl_down(best, off); int oi = __shfl_down(bi, off);
        if (ov < best || (ov == best && oi < bi)) { best = ov; bi = oi; }
    }
    if (lane == 0) ((int*)W)[W_BATCH + (size_t)b*SB + PB_VIND + v] = bi;
}

__global__ void k_align(const float* __restrict__ pose, float* W) {
    int v = blockIdx.x, b = blockIdx.y;
    float* WB = W + W_BATCH + (size_t)b*SB;
    int* IB = (int*)W + W_BATCH + (size_t)b*SB;
    int vi = IB[PB_VIND + v];
    const float* P = pose + 12*b;
    __shared__ float rtr[NA][9];
    __shared__ float tk[NA][12], tks[NA][12];
    int a = threadIdx.x;
    if (a < NA) {
        const float* G = W + W_GROT + 9*(vi*NA + a);
        float rt[9];
#pragma unroll
        for (int i=0;i<3;++i)
#pragma unroll
            for (int j=0;j<3;++j)
                rt[i*3+j] = P[i*4+0]*G[0*3+j] + P[i*4+1]*G[1*3+j] + P[i*4+2]*G[2*3+j];
#pragma unroll
        for (int q=0;q<9;++q) rtr[a][q]=rt[q];
        float t1[12], t2[12];
        kp12(rt, C_L, t1); kp12(rt, C_LS, t2);
#pragma unroll
        for (int k=0;k<12;++k) { tk[a][k]=t1[k]; tks[a][k]=t2[k]; }
    }
    __syncthreads();
    if (a < NA) {
        const float* pk = W + W_PKP + 12*(v*NA + a);
        float pkl[12];
#pragma unroll
        for (int k=0;k<12;++k) pkl[k]=pk[k];
        float m1=INFINITY, m2=INFINITY; int i1=0, i2=0;
        for (int ap=0; ap<NA; ++ap) {
            float d1=0.f, d2=0.f;
#pragma unroll
            for (int k=0;k<12;++k) {
                float e1 = pkl[k]-tk[ap][k];  d1 += e1*e1;
                float e2 = pkl[k]-tks[ap][k]; d2 += e2*e2;
            }
            if (d1 < m1) { m1=d1; i1=ap; }
            if (d2 < m2) { m2=d2; i2=ap; }
        }
        int ind = (m1 < m2) ? i1 : i2;
        int mi = v*NA + a;
        IB[PB_AIND + mi] = ind;
        float sel[9];
#pragma unroll
        for (int q=0;q<9;++q) { sel[q]=rtr[ind][q]; WB[PB_ROT + 9*mi + q] = sel[q]; }
        float tb[12], tbs[12];
        kp12(sel, C_L, tb); kp12(sel, C_LS, tbs);
        float s1=0.f, s2=0.f;
#pragma unroll
        for (int k=0;k<12;++k) {
            WB[PB_TB +k*NM+mi]=tb[k];  s1 += tb[k]*tb[k];   // transposed [12][NM]
            WB[PB_TBS+k*NM+mi]=tbs[k]; s2 += tbs[k]*tbs[k]; // transposed [12][NM]
        }
        WB[PB_TN1+mi]=s1; WB[PB_TN2+mi]=s2;
    }
}

// wave-per-seed NN: 4 waves/block, LDS-staged grasp points
__global__ void k_nn(const float* __restrict__ pc, float* W) {
    int b = blockIdx.y;
    float* WB = W + W_BATCH + (size_t)b*SB;
    __shared__ float gx[NG], gy[NG], gz[NG], gn[NG];
    for (int i = threadIdx.x; i < NG; i += 256) {
        float x = WB[PB_GPT+3*i], y = WB[PB_GPT+3*i+1], z = WB[PB_GPT+3*i+2];
        gx[i]=x; gy[i]=y; gz[i]=z; gn[i]=x*x+y*y+z*z;
    }
    __syncthreads();
    int wv = threadIdx.x >> 6, lane = threadIdx.x & 63;
    int s = blockIdx.x*4 + wv;
    float px = pc[((size_t)b*NS+s)*3+0], py = pc[((size_t)b*NS+s)*3+1], pz = pc[((size_t)b*NS+s)*3+2];
    float pn = px*px+py*py+pz*pz;
    float best = INFINITY; int bi = 0x7fffffff;
    for (int g = lane; g < NG; g += 64) {
        float d = pn + gn[g] - 2.f*(px*gx[g]+py*gy[g]+pz*gz[g]);
        if (d < best) { best = d; bi = g; }
    }
#pragma unroll
    for (int off = 32; off > 0; off >>= 1) {
        float ov = __shfl_down(best, off); int oi = __shfl_down(bi, off);
        if (ov < best || (ov == best && oi < bi)) { best = ov; bi = oi; }
    }
    if (lane == 0) ((int*)W)[W_BATCH + (size_t)b*SB + PB_NN + s] = bi;
}

// one seed per 256-thread block; float4 loads over transposed TB/TBS
__global__ void k_final(const float* __restrict__ r6p, const float* __restrict__ dpp,
                        const float* __restrict__ labels, const float* __restrict__ offsets,
                        float* __restrict__ W, float* __restrict__ out, int B) {
    int b = blockIdx.y;
    int s = blockIdx.x;
    int tid = threadIdx.x;
    int wv = tid >> 6, lane = tid & 63;
    float* WB = W + W_BATCH + (size_t)b*SB;
    const int* IB = (const int*)W + W_BATCH + (size_t)b*SB;

    // all threads compute pb redundantly (cheap)
    const float* r6 = r6p + 6*((size_t)b*NS+s);
    float a1x=r6[0],a1y=r6[1],a1z=r6[2],a2x=r6[3],a2y=r6[4],a2z=r6[5];
    float n1 = sqrtf(a1x*a1x+a1y*a1y+a1z*a1z);
    float b1x=a1x/n1, b1y=a1y/n1, b1z=a1z/n1;
    float dt = b1x*a2x+b1y*a2y+b1z*a2z;
    float p2x=a2x-dt*b1x, p2y=a2y-dt*b1y, p2z=a2z-dt*b1z;
    float n2 = sqrtf(p2x*p2x+p2y*p2y+p2z*p2z);
    float b2x=p2x/n2, b2y=p2y/n2, b2z=p2z/n2;
    float b3x=b1y*b2z-b1z*b2y, b3y=b1z*b2x-b1x*b2z, b3z=b1x*b2y-b1y*b2x;
    float Rp[9] = {b1x,b1y,b1z, b2x,b2y,b2z, b3x,b3y,b3z};
    float pb[12]; kp12(Rp, C_L, pb);
    float Pn = 0.f;
#pragma unroll
    for (int k=0;k<12;++k) Pn += pb[k]*pb[k];

    float m1=INFINITY, m2=INFINITY; int i1=0x7fffffff, i2=0x7fffffff;
#pragma unroll
    for (int it = 0; it < 4; ++it) {
        int j0 = it*1024 + tid*4;
        if (j0 < NM) {
            float dot1[4] = {0.f,0.f,0.f,0.f};
            float dot2[4] = {0.f,0.f,0.f,0.f};
#pragma unroll
            for (int k=0;k<12;++k) {
                float4 tb  = *reinterpret_cast<const float4*>(&WB[PB_TB  + k*NM + j0]);
                float4 tbs = *reinterpret_cast<const float4*>(&WB[PB_TBS + k*NM + j0]);
                dot1[0] += pb[k]*tb.x;  dot1[1] += pb[k]*tb.y;
                dot1[2] += pb[k]*tb.z;  dot1[3] += pb[k]*tb.w;
                dot2[0] += pb[k]*tbs.x; dot2[1] += pb[k]*tbs.y;
                dot2[2] += pb[k]*tbs.z; dot2[3] += pb[k]*tbs.w;
            }
            float4 tn1 = *reinterpret_cast<const float4*>(&WB[PB_TN1 + j0]);
            float4 tn2 = *reinterpret_cast<const float4*>(&WB[PB_TN2 + j0]);
            float n1v[4] = {tn1.x,tn1.y,tn1.z,tn1.w};
            float n2v[4] = {tn2.x,tn2.y,tn2.z,tn2.w};
#pragma unroll
            for (int q=0;q<4;++q) {
                float d1 = Pn + n1v[q] - 2.f*dot1[q];
                float d2 = Pn + n2v[q] - 2.f*dot2[q];
                int j = j0 + q;
                if (d1 < m1) { m1=d1; i1=j; }
                if (d2 < m2) { m2=d2; i2=j; }
            }
        }
    }
    // wave reduce (val asc, idx tie -> smaller)
#pragma unroll
    for (int off = 32; off > 0; off >>= 1) {
        float o1 = __shfl_down(m1, off); int oi1 = __shfl_down(i1, off);
        if (o1 < m1 || (o1 == m1 && oi1 < i1)) { m1 = o1; i1 = oi1; }
        float o2 = __shfl_down(m2, off); int oi2 = __shfl_down(i2, off);
        if (o2 < m2 || (o2 == m2 && oi2 < i2)) { m2 = o2; i2 = oi2; }
    }
    // cross-wave merge via LDS, in wave order
    __shared__ float sm1[4], sm2[4];
    __shared__ int   si1[4], si2[4];
    if (lane == 0) { sm1[wv]=m1; si1[wv]=i1; sm2[wv]=m2; si2[wv]=i2; }
    __syncthreads();
    if (tid != 0) return;
#pragma unroll
    for (int w = 1; w < 4; ++w) {
        if (sm1[w] < m1 || (sm1[w] == m1 && si1[w] < i1)) { m1 = sm1[w]; i1 = si1[w]; }
        if (sm2[w] < m2 || (sm2[w] == m2 && si2[w] < i2)) { m2 = sm2[w]; i2 = si2[w]; }
    }
    int rot_ind = (m1 < m2) ? i1 : i2;

    float dp = dpp[(size_t)b*NS+s];
    float bd = INFINITY; int di = 0;
#pragma unroll
    for (int d = 0; d < ND; ++d) {
        float dv = (float)(0.01 + 0.01*(double)d);
        float ad = fabsf(dp - dv);
        if (ad < bd) { bd = ad; di = d; }
    }

    int nn_s = IB[PB_NN+s];
    int v_out = rot_ind / NA;
    int vi = IB[PB_VIND + v_out];
    int ai = IB[PB_AIND + rot_ind];
    size_t lidx = ((((size_t)b*NG+nn_s)*NV + vi)*NA + ai)*ND + di;
    float gs = labels[lidx];
    float gw = offsets[lidx];

    int bs = b*NS + s;
    int oRot = B*NS*3;
    int oSc  = oRot + B*NS*6;
    int oWd  = oSc  + B*NS;
    int oDp  = oWd  + B*NS;
    int oWid = oDp  + B*NS;
    int oSid = oWid + B*NS;

    const float* gsel = WB + PB_GPT + 3*nn_s;
    out[3*bs+0]=gsel[0]; out[3*bs+1]=gsel[1]; out[3*bs+2]=gsel[2];
    const float* Rsel = WB + PB_ROT + 9*rot_ind;
#pragma unroll
    for (int q=0;q<6;++q) out[oRot + 6*bs + q] = Rsel[q];

    bool mask = (gs > 0.f) && (gw <= 0.1f);
    float sc = mask ? (1.1f - gs) : 0.f;
    out[oSc + bs] = sc;
    out[oWd + bs] = gw;
    out[oDp + bs] = (float)(0.01 + 0.01*(double)di);

    int wid = 0;
    wid += (0.02f < gw); wid += (0.04f < gw); wid += (0.06f < gw); wid += (0.08f < gw);
    const float sbins[9] = {0.1f,0.2f,0.3f,0.4f,0.5f,0.6f,0.7f,0.8f,0.9f};
    int sid = 0;
#pragma unroll
    for (int i=0;i<9;++i) sid += (sbins[i] < sc) ? 1 : 0;
    out[oWid + bs] = (float)wid;
    out[oSid + bs] = (float)sid;
}

extern "C" void kernel_launch(void* const* d_in, const int* in_sizes, int n_in,
                              void* d_out, int out_size, void* d_ws, size_t ws_size,
                              hipStream_t stream) {
    const float* pc      = (const float*)d_in[0];
    const float* pose    = (const float*)d_in[1];
    const float* gp      = (const float*)d_in[2];
    const float* labels  = (const float*)d_in[3];
    const float* offsets = (const float*)d_in[4];
    const float* r6      = (const float*)d_in[5];
    const float* dpp     = (const float*)d_in[6];
    float* W   = (float*)d_ws;
    float* out = (float*)d_out;
    int B = in_sizes[1] / 12;

    hipLaunchKernelGGL(k_views, dim3(2), dim3(256), 0, stream, W);
    hipLaunchKernelGGL(k_grot,  dim3((NM+255)/256), dim3(256), 0, stream, W);
    hipLaunchKernelGGL(k_gpt,   dim3(NG/256, B), dim3(256), 0, stream, pose, gp, W);
    hipLaunchKernelGGL(k_vind,  dim3(NV/4, B), dim3(256), 0, stream, pose, W);
    hipLaunchKernelGGL(k_align, dim3(NV, B), dim3(64), 0, stream, pose, W);
    hipLaunchKernelGGL(k_nn,    dim3(NS/4, B), dim3(256), 0, stream, pc, W);
    hipLaunchKernelGGL(k_final, dim3(NS, B), dim3(256), 0, stream, r6, dpp, labels, offsets, W, out, B);
}

// Round 10
// 260.683 us; speedup vs baseline: 3.9819x; 1.0217x over previous
//
#include <hip/hip_runtime.h>

#define NV 300
#define NA 12
#define ND 4
#define NM (NV*NA)
#define NS 1024
#define NG 1024

// workspace float offsets
#define W_VIEWS 0          // 900
#define W_GROT  900        // 32400
#define W_PKP   33300      // 43200
#define W_BATCH 76500
#define SB      134032     // per-batch stride (floats)

#define PB_GPT  0          // 3072
#define PB_ROT  3072       // 32400
#define PB_TB   35472      // 43200 (transposed: [12][NM])
#define PB_TBS  78672      // 43200 (transposed: [12][NM])
#define PB_TN1  121872     // 3600
#define PB_TN2  125472     // 3600
#define PB_VIND 129072     // 300 ints
#define PB_AIND 129372     // 3600 ints
#define PB_NN   132972     // 1024 ints

__constant__ float C_L[4][3]  = {{0.02f,0.f,0.f},{0.02f,0.01f,0.f},{0.02f,-0.01f,0.f},{0.f,0.f,0.f}};
__constant__ float C_LS[4][3] = {{0.02f,0.f,0.f},{0.02f,-0.01f,0.f},{0.02f,0.01f,0.f},{0.f,0.f,0.f}};

__device__ __forceinline__ void kp12(const float R[9], const float (*L)[3], float out[12]) {
#pragma unroll
    for (int k = 0; k < 4; ++k)
#pragma unroll
        for (int i = 0; i < 3; ++i)
            out[k*3+i] = R[i*3+0]*L[k][0] + R[i*3+1]*L[k][1] + R[i*3+2]*L[k][2];
}

// fp64 Fibonacci-sphere view i (identical formula to numpy reference)
__device__ __forceinline__ void view_d(int i, float* vx, float* vy, float* vz) {
    const double PI = 3.14159265358979323846;
    double phi = (sqrt(5.0) - 1.0) * 0.5;
    double z = (2.0*i + 1.0)/(double)NV - 1.0;
    double r2 = 1.0 - z*z; r2 = r2 > 0.0 ? r2 : 0.0;
    double r = sqrt(r2);
    double ang = 2.0*PI*(double)i*phi;
    *vx = (float)(r*cos(ang));
    *vy = (float)(r*sin(ang));
    *vz = (float)z;
}

// K1: blocks 0..14 -> views + GRASP_ROT + pkp; blocks 15.. -> gp_trans
__global__ void k_setup(const float* __restrict__ pose, const float* __restrict__ gp,
                        float* W) {
    int bid = blockIdx.x;
    if (bid < 15) {
        int m = bid*256 + threadIdx.x;
        if (m >= NM) return;
        if (m < NV) {
            float x,y,z; view_d(m, &x,&y,&z);
            W[W_VIEWS + 3*m+0] = x; W[W_VIEWS + 3*m+1] = y; W[W_VIEWS + 3*m+2] = z;
        }
        int vi = m / NA, ai = m % NA;
        float vx,vy,vz; view_d(vi, &vx,&vy,&vz);
        float tx = -vx, ty = -vy, tz = -vz;
        float nrm = sqrtf(tx*tx + ty*ty + tz*tz);
        float ax0 = tx/nrm, ax1 = ty/nrm, ax2 = tz/nrm;
        float ay0 = -ax1, ay1 = ax0, ay2 = 0.f;
        float n2 = sqrtf(ay0*ay0 + ay1*ay1 + ay2*ay2);
        if (n2 > 1e-8f) { float d = fmaxf(n2, 1e-12f); ay0 /= d; ay1 /= d; ay2 /= d; }
        else { ay0 = 0.f; ay1 = 1.f; ay2 = 0.f; }
        float az0 = ax1*ay2 - ax2*ay1;
        float az1 = ax2*ay0 - ax0*ay2;
        float az2 = ax0*ay1 - ax1*ay0;
        float angle = (float)(3.14159265358979323846/12.0*(double)ai);
        float c = cosf(angle), s = sinf(angle);
        float G[9];
        G[0]=ax0; G[1]=ay0*c+az0*s; G[2]=-ay0*s+az0*c;
        G[3]=ax1; G[4]=ay1*c+az1*s; G[5]=-ay1*s+az1*c;
        G[6]=ax2; G[7]=ay2*c+az2*s; G[8]=-ay2*s+az2*c;
#pragma unroll
        for (int q=0;q<9;++q) W[W_GROT + 9*m + q] = G[q];
        float pk[12]; kp12(G, C_L, pk);
#pragma unroll
        for (int q=0;q<12;++q) W[W_PKP + 12*m + q] = pk[q];
    } else {
        int idx = (bid-15)*256 + threadIdx.x;   // over B*NG
        int b = idx >> 10, g = idx & (NG-1);
        const float* P = pose + 12*b;
        float x = gp[(size_t)idx*3+0], y = gp[(size_t)idx*3+1], z = gp[(size_t)idx*3+2];
        float* o = W + W_BATCH + (size_t)b*SB + PB_GPT + 3*g;
        o[0] = P[0]*x + P[1]*y + P[2]*z  + P[3];
        o[1] = P[4]*x + P[5]*y + P[6]*z  + P[7];
        o[2] = P[8]*x + P[9]*y + P[10]*z + P[11];
    }
}

// K2: fused vind + align. one 64-thread block per (v, b)
__global__ void k_va(const float* __restrict__ pose, float* W) {
    int v = blockIdx.x, b = blockIdx.y;
    float* WB = W + W_BATCH + (size_t)b*SB;
    int* IB = (int*)W + W_BATCH + (size_t)b*SB;
    const float* P = pose + 12*b;
    int lane = threadIdx.x;  // 0..63, one wave

    __shared__ float vtx[NV], vty[NV], vtz[NV], vn[NV];
    __shared__ float rtr[NA][9];
    __shared__ float tk[NA][12], tks[NA][12];
    __shared__ int s_vi;

    for (int i = lane; i < NV; i += 64) {
        float x = W[W_VIEWS+3*i], y = W[W_VIEWS+3*i+1], z = W[W_VIEWS+3*i+2];
        float a = P[0]*x+P[1]*y+P[2]*z;
        float c = P[4]*x+P[5]*y+P[6]*z;
        float d = P[8]*x+P[9]*y+P[10]*z;
        vtx[i]=a; vty[i]=c; vtz[i]=d;
        vn[i] = a*a + c*c + d*d;
    }
    __syncthreads();
    {
        float x = W[W_VIEWS+3*v], y = W[W_VIEWS+3*v+1], z = W[W_VIEWS+3*v+2];
        float na = x*x + y*y + z*z;
        float best = INFINITY; int bi = 0x7fffffff;
        for (int v2 = lane; v2 < NV; v2 += 64) {
            float d = na + vn[v2] - 2.f*(x*vtx[v2] + y*vty[v2] + z*vtz[v2]);
            if (d < best) { best = d; bi = v2; }
        }
#pragma unroll
        for (int off = 32; off > 0; off >>= 1) {
            float ov = __shfl_down(best, off); int oi = __shfl_down(bi, off);
            if (ov < best || (ov == best && oi < bi)) { best = ov; bi = oi; }
        }
        if (lane == 0) { s_vi = bi; IB[PB_VIND + v] = bi; }
    }
    __syncthreads();
    int vi = s_vi;
    int a = lane;
    if (a < NA) {
        const float* G = W + W_GROT + 9*(vi*NA + a);
        float rt[9];
#pragma unroll
        for (int i=0;i<3;++i)
#pragma unroll
            for (int j=0;j<3;++j)
                rt[i*3+j] = P[i*4+0]*G[0*3+j] + P[i*4+1]*G[1*3+j] + P[i*4+2]*G[2*3+j];
#pragma unroll
        for (int q=0;q<9;++q) rtr[a][q]=rt[q];
        float t1[12], t2[12];
        kp12(rt, C_L, t1); kp12(rt, C_LS, t2);
#pragma unroll
        for (int k=0;k<12;++k) { tk[a][k]=t1[k]; tks[a][k]=t2[k]; }
    }
    __syncthreads();
    if (a < NA) {
        const float* pk = W + W_PKP + 12*(v*NA + a);
        float pkl[12];
#pragma unroll
        for (int k=0;k<12;++k) pkl[k]=pk[k];
        float m1=INFINITY, m2=INFINITY; int i1=0, i2=0;
        for (int ap=0; ap<NA; ++ap) {
            float d1=0.f, d2=0.f;
#pragma unroll
            for (int k=0;k<12;++k) {
                float e1 = pkl[k]-tk[ap][k];  d1 += e1*e1;
                float e2 = pkl[k]-tks[ap][k]; d2 += e2*e2;
            }
            if (d1 < m1) { m1=d1; i1=ap; }
            if (d2 < m2) { m2=d2; i2=ap; }
        }
        int ind = (m1 < m2) ? i1 : i2;
        int mi = v*NA + a;
        IB[PB_AIND + mi] = ind;
        float sel[9];
#pragma unroll
        for (int q=0;q<9;++q) { sel[q]=rtr[ind][q]; WB[PB_ROT + 9*mi + q] = sel[q]; }
        float tb[12], tbs[12];
        kp12(sel, C_L, tb); kp12(sel, C_LS, tbs);
        float s1=0.f, s2=0.f;
#pragma unroll
        for (int k=0;k<12;++k) {
            WB[PB_TB +k*NM+mi]=tb[k];  s1 += tb[k]*tb[k];   // transposed [12][NM]
            WB[PB_TBS+k*NM+mi]=tbs[k]; s2 += tbs[k]*tbs[k]; // transposed [12][NM]
        }
        WB[PB_TN1+mi]=s1; WB[PB_TN2+mi]=s2;
    }
}

// K3: fused nn + final. one 256-thread block per (s, b)
__global__ void k_nf(const float* __restrict__ pc,
                     const float* __restrict__ r6p, const float* __restrict__ dpp,
                     const float* __restrict__ labels, const float* __restrict__ offsets,
                     float* __restrict__ W, float* __restrict__ out, int B) {
    int b = blockIdx.y;
    int s = blockIdx.x;
    int tid = threadIdx.x;
    int wv = tid >> 6, lane = tid & 63;
    float* WB = W + W_BATCH + (size_t)b*SB;
    const int* IB = (const int*)W + W_BATCH + (size_t)b*SB;

    __shared__ float gx[NG], gy[NG], gz[NG], gn[NG];
    for (int i = tid; i < NG; i += 256) {
        float x = WB[PB_GPT+3*i], y = WB[PB_GPT+3*i+1], z = WB[PB_GPT+3*i+2];
        gx[i]=x; gy[i]=y; gz[i]=z; gn[i]=x*x+y*y+z*z;
    }
    __syncthreads();

    // --- nn scan: 256 threads, stride 256 ---
    float px = pc[((size_t)b*NS+s)*3+0], py = pc[((size_t)b*NS+s)*3+1], pz = pc[((size_t)b*NS+s)*3+2];
    float pn = px*px+py*py+pz*pz;
    float nbest = INFINITY; int nbi = 0x7fffffff;
    for (int g = tid; g < NG; g += 256) {
        float d = pn + gn[g] - 2.f*(px*gx[g]+py*gy[g]+pz*gz[g]);
        if (d < nbest) { nbest = d; nbi = g; }
    }
#pragma unroll
    for (int off = 32; off > 0; off >>= 1) {
        float ov = __shfl_down(nbest, off); int oi = __shfl_down(nbi, off);
        if (ov < nbest || (ov == nbest && oi < nbi)) { nbest = ov; nbi = oi; }
    }
    __shared__ float snv[4]; __shared__ int sni[4];
    if (lane == 0) { snv[wv] = nbest; sni[wv] = nbi; }

    // --- rot match: pb from rot6d (all threads, redundant) ---
    const float* r6 = r6p + 6*((size_t)b*NS+s);
    float a1x=r6[0],a1y=r6[1],a1z=r6[2],a2x=r6[3],a2y=r6[4],a2z=r6[5];
    float n1 = sqrtf(a1x*a1x+a1y*a1y+a1z*a1z);
    float b1x=a1x/n1, b1y=a1y/n1, b1z=a1z/n1;
    float dt = b1x*a2x+b1y*a2y+b1z*a2z;
    float p2x=a2x-dt*b1x, p2y=a2y-dt*b1y, p2z=a2z-dt*b1z;
    float n2 = sqrtf(p2x*p2x+p2y*p2y+p2z*p2z);
    float b2x=p2x/n2, b2y=p2y/n2, b2z=p2z/n2;
    float b3x=b1y*b2z-b1z*b2y, b3y=b1z*b2x-b1x*b2z, b3z=b1x*b2y-b1y*b2x;
    float Rp[9] = {b1x,b1y,b1z, b2x,b2y,b2z, b3x,b3y,b3z};
    float pb[12]; kp12(Rp, C_L, pb);
    float Pn = 0.f;
#pragma unroll
    for (int k=0;k<12;++k) Pn += pb[k]*pb[k];

    float m1=INFINITY, m2=INFINITY; int i1=0x7fffffff, i2=0x7fffffff;
#pragma unroll
    for (int it = 0; it < 4; ++it) {
        int j0 = it*1024 + tid*4;
        if (j0 < NM) {
            float dot1[4] = {0.f,0.f,0.f,0.f};
            float dot2[4] = {0.f,0.f,0.f,0.f};
#pragma unroll
            for (int k=0;k<12;++k) {
                float4 tb  = *reinterpret_cast<const float4*>(&WB[PB_TB  + k*NM + j0]);
                float4 tbs = *reinterpret_cast<const float4*>(&WB[PB_TBS + k*NM + j0]);
                dot1[0] += pb[k]*tb.x;  dot1[1] += pb[k]*tb.y;
                dot1[2] += pb[k]*tb.z;  dot1[3] += pb[k]*tb.w;
                dot2[0] += pb[k]*tbs.x; dot2[1] += pb[k]*tbs.y;
                dot2[2] += pb[k]*tbs.z; dot2[3] += pb[k]*tbs.w;
            }
            float4 tn1 = *reinterpret_cast<const float4*>(&WB[PB_TN1 + j0]);
            float4 tn2 = *reinterpret_cast<const float4*>(&WB[PB_TN2 + j0]);
            float n1v[4] = {tn1.x,tn1.y,tn1.z,tn1.w};
            float n2v[4] = {tn2.x,tn2.y,tn2.z,tn2.w};
#pragma unroll
            for (int q=0;q<4;++q) {
                float d1 = Pn + n1v[q] - 2.f*dot1[q];
                float d2 = Pn + n2v[q] - 2.f*dot2[q];
                int j = j0 + q;
                if (d1 < m1) { m1=d1; i1=j; }
                if (d2 < m2) { m2=d2; i2=j; }
            }
        }
    }
#pragma unroll
    for (int off = 32; off > 0; off >>= 1) {
        float o1 = __shfl_down(m1, off); int oi1 = __shfl_down(i1, off);
        if (o1 < m1 || (o1 == m1 && oi1 < i1)) { m1 = o1; i1 = oi1; }
        float o2 = __shfl_down(m2, off); int oi2 = __shfl_down(i2, off);
        if (o2 < m2 || (o2 == m2 && oi2 < i2)) { m2 = o2; i2 = oi2; }
    }
    __shared__ float sm1[4], sm2[4];
    __shared__ int   si1[4], si2[4];
    if (lane == 0) { sm1[wv]=m1; si1[wv]=i1; sm2[wv]=m2; si2[wv]=i2; }
    __syncthreads();
    if (tid != 0) return;
#pragma unroll
    for (int w = 1; w < 4; ++w) {
        if (sm1[w] < m1 || (sm1[w] == m1 && si1[w] < i1)) { m1 = sm1[w]; i1 = si1[w]; }
        if (sm2[w] < m2 || (sm2[w] == m2 && si2[w] < i2)) { m2 = sm2[w]; i2 = si2[w]; }
        if (snv[w] < nbest || (snv[w] == nbest && sni[w] < nbi)) { nbest = snv[w]; nbi = sni[w]; }
    }
    int rot_ind = (m1 < m2) ? i1 : i2;
    int nn_s = nbi;

    float dp = dpp[(size_t)b*NS+s];
    float bd = INFINITY; int di = 0;
#pragma unroll
    for (int d = 0; d < ND; ++d) {
        float dv = (float)(0.01 + 0.01*(double)d);
        float ad = fabsf(dp - dv);
        if (ad < bd) { bd = ad; di = d; }
    }

    int v_out = rot_ind / NA;
    int vi = IB[PB_VIND + v_out];
    int ai = IB[PB_AIND + rot_ind];
    size_t lidx = ((((size_t)b*NG+nn_s)*NV + vi)*NA + ai)*ND + di;
    float gs = labels[lidx];
    float gw = offsets[lidx];

    int bs = b*NS + s;
    int oRot = B*NS*3;
    int oSc  = oRot + B*NS*6;
    int oWd  = oSc  + B*NS;
    int oDp  = oWd  + B*NS;
    int oWid = oDp  + B*NS;
    int oSid = oWid + B*NS;

    out[3*bs+0]=gx[nn_s]; out[3*bs+1]=gy[nn_s]; out[3*bs+2]=gz[nn_s];
    const float* Rsel = WB + PB_ROT + 9*rot_ind;
#pragma unroll
    for (int q=0;q<6;++q) out[oRot + 6*bs + q] = Rsel[q];

    bool mask = (gs > 0.f) && (gw <= 0.1f);
    float sc = mask ? (1.1f - gs) : 0.f;
    out[oSc + bs] = sc;
    out[oWd + bs] = gw;
    out[oDp + bs] = (float)(0.01 + 0.01*(double)di);

    int wid = 0;
    wid += (0.02f < gw); wid += (0.04f < gw); wid += (0.06f < gw); wid += (0.08f < gw);
    const float sbins[9] = {0.1f,0.2f,0.3f,0.4f,0.5f,0.6f,0.7f,0.8f,0.9f};
    int sid = 0;
#pragma unroll
    for (int i=0;i<9;++i) sid += (sbins[i] < sc) ? 1 : 0;
    out[oWid + bs] = (float)wid;
    out[oSid + bs] = (float)sid;
}

extern "C" void kernel_launch(void* const* d_in, const int* in_sizes, int n_in,
                              void* d_out, int out_size, void* d_ws, size_t ws_size,
                              hipStream_t stream) {
    const float* pc      = (const float*)d_in[0];
    const float* pose    = (const float*)d_in[1];
    const float* gp      = (const float*)d_in[2];
    const float* labels  = (const float*)d_in[3];
    const float* offsets = (const float*)d_in[4];
    const float* r6      = (const float*)d_in[5];
    const float* dpp     = (const float*)d_in[6];
    float* W   = (float*)d_ws;
    float* out = (float*)d_out;
    int B = in_sizes[1] / 12;

    hipLaunchKernelGGL(k_setup, dim3(15 + B*(NG/256)), dim3(256), 0, stream, pose, gp, W);
    hipLaunchKernelGGL(k_va,    dim3(NV, B), dim3(64), 0, stream, pose, W);
    hipLaunchKernelGGL(k_nf,    dim3(NS, B), dim3(256), 0, stream,
                       pc, r6, dpp, labels, offsets, W, out, B);
}